// Round 12
// baseline (530.047 us; speedup 1.0000x reference)
//
#include <hip/hip_runtime.h>
#include <hip/hip_bf16.h>

#define NNODES 50000
#define NEDGES 800000
#define FIN    128
#define HID    64
#define HEADS  4
#define NGRAPH 256
#define NCLS   10
#define DTOT   256   // HEADS*HID
#define ALPHA  0.01f
#define CAPLG  6          // 64 slots/node bin; Poisson(16) => P(deg>64) ~ 1e-20
#define CAP    (1 << CAPLG)
#define BINS   (NNODES << CAPLG)   // 3.2M slots
#define NGROUP 64                  // nodes per gather block
#define GRPS   ((NNODES + NGROUP - 1) / NGROUP)   // 782

typedef short bf16x8 __attribute__((ext_vector_type(8)));
typedef float f32x4  __attribute__((ext_vector_type(4)));

#define NB      ((NNODES + 255) / 256)      // 196
#define EB      ((NEDGES + 255) / 256)      // 3125
#define XB      ((NNODES * FIN / 4 + 255) / 256)  // 6250
#define W1B     (FIN * DTOT / 256)          // 128
#define W2B     (DTOT * DTOT / 256)         // 256

__device__ __forceinline__ ushort f2bf(float v) {
    return __bfloat16_as_ushort(__float2bfloat16(v));
}
__device__ __forceinline__ float blo(unsigned u) { return __uint_as_float(u << 16); }
__device__ __forceinline__ float bhi(unsigned u) { return __uint_as_float(u & 0xffff0000u); }

// ---------------- fused setup: edge binning (ushort) | gstart | cast x | transpose W1,W2 ----------------
__global__ __launch_bounds__(256) void k_setup(const int* __restrict__ src, const int* __restrict__ dst,
                                               int* __restrict__ cursor, ushort* __restrict__ esrc,
                                               const int* __restrict__ batch, int* __restrict__ gstart,
                                               const float4* __restrict__ x4, ushort4* __restrict__ xbf4,
                                               const float* __restrict__ W1, ushort* __restrict__ W1t,
                                               const float* __restrict__ W2, ushort* __restrict__ W2t) {
    int b = blockIdx.x, t = threadIdx.x;
    if (b < EB) {
        int e = b * 256 + t;
        if (e < NEDGES) {
            int d = dst[e];
            int pos = atomicAdd(&cursor[d], 1);
            if (pos < CAP) esrc[(d << CAPLG) + pos] = (ushort)src[e];
        }
    } else if (b < EB + NB) {
        int i = (b - EB) * 256 + t;
        if (i >= NNODES) return;
        int bb = batch[i];
        if (i == 0) {
            for (int g = 0; g <= bb; ++g) gstart[g] = 0;
        } else {
            int pb = batch[i - 1];
            if (pb != bb) for (int g = pb + 1; g <= bb; ++g) gstart[g] = i;
        }
        if (i == NNODES - 1)
            for (int g = bb + 1; g <= NGRAPH; ++g) gstart[g] = NNODES;
    } else if (b < EB + NB + XB) {
        int i = (b - EB - NB) * 256 + t;
        if (i >= NNODES * FIN / 4) return;
        float4 v = x4[i];
        ushort4 o;
        o.x = f2bf(v.x); o.y = f2bf(v.y); o.z = f2bf(v.z); o.w = f2bf(v.w);
        xbf4[i] = o;
    } else if (b < EB + NB + XB + W1B) {
        int id = (b - EB - NB - XB) * 256 + t;
        int n = id & 255, k = id >> 8;
        W1t[n * FIN + (((k >> 3) ^ (n & 7)) << 3) + (k & 7)] = f2bf(W1[k * DTOT + n]);
    } else {
        int id = (b - EB - NB - XB - W1B) * 256 + t;
        int n = id & 255, k = id >> 8;
        W2t[n * DTOT + (((k >> 3) ^ (n & 7)) << 3) + (k & 7)] = f2bf(W2[k * DTOT + n]);
    }
}

// ---------------- MFMA GEMM: Cbf[M,256] = Abf[M,K] @ W[K,256], tile 128x128 (2 heads) ----------------
template <int K>
__global__ __launch_bounds__(256) void k_gemm_mfma(const ushort* __restrict__ Abf,
                                                   const ushort* __restrict__ Bt,
                                                   ushort* __restrict__ Cbf,
                                                   float* __restrict__ ls,
                                                   float* __restrict__ ld_,
                                                   const float* __restrict__ a_src,
                                                   const float* __restrict__ a_dst,
                                                   int M) {
    __shared__ ushort Bl[128 * K];
    const int tid  = threadIdx.x;
    const int w    = tid >> 6;
    const int lane = tid & 63;
    const int l15  = lane & 15;
    const int quad = lane >> 4;
    const int m0 = blockIdx.y * 128;
    const int n0 = blockIdx.x * 128;
    const int hb = blockIdx.x * 2;

    {
        const uint4* sp = (const uint4*)(Bt + (size_t)n0 * K);
        uint4* dp = (uint4*)Bl;
#pragma unroll
        for (int idx = tid; idx < 128 * K / 8; idx += 256) dp[idx] = sp[idx];
    }
    __syncthreads();

    f32x4 acc[2][8];
#pragma unroll
    for (int mf = 0; mf < 2; ++mf)
#pragma unroll
        for (int nf = 0; nf < 8; ++nf)
            acc[mf][nf] = (f32x4){0.f, 0.f, 0.f, 0.f};

    const int rbase = m0 + w * 32;
    int rowA0 = rbase + l15;       if (rowA0 >= M) rowA0 = M - 1;
    int rowA1 = rbase + 16 + l15;  if (rowA1 >= M) rowA1 = M - 1;
    const ushort* pa0 = Abf + (size_t)rowA0 * K + quad * 8;
    const ushort* pa1 = Abf + (size_t)rowA1 * K + quad * 8;

#pragma unroll
    for (int ks = 0; ks < K / 32; ++ks) {
        bf16x8 a0 = *(const bf16x8*)(pa0 + ks * 32);
        bf16x8 a1 = *(const bf16x8*)(pa1 + ks * 32);
        bf16x8 bfr[8];
#pragma unroll
        for (int nf = 0; nf < 8; ++nf) {
            int n = nf * 16 + l15;
            int c = (ks * 4 + quad) ^ (n & 7);
            bfr[nf] = *(const bf16x8*)&Bl[n * K + (c << 3)];
        }
#pragma unroll
        for (int nf = 0; nf < 8; ++nf) {
            acc[0][nf] = __builtin_amdgcn_mfma_f32_16x16x32_bf16(a0, bfr[nf], acc[0][nf], 0, 0, 0);
            acc[1][nf] = __builtin_amdgcn_mfma_f32_16x16x32_bf16(a1, bfr[nf], acc[1][nf], 0, 0, 0);
        }
    }

    float as[8], ad[8];
#pragma unroll
    for (int nf = 0; nf < 8; ++nf) {
        int head = hb + (nf >> 2);
        as[nf] = a_src[head * HID + (nf & 3) * 16 + l15];
        ad[nf] = a_dst[head * HID + (nf & 3) * 16 + l15];
    }
#pragma unroll
    for (int mf = 0; mf < 2; ++mf) {
#pragma unroll
        for (int reg = 0; reg < 4; ++reg) {
            int row = rbase + mf * 16 + quad * 4 + reg;
            bool ok = row < M;
            if (ok) {
#pragma unroll
                for (int nf = 0; nf < 8; ++nf)
                    Cbf[(size_t)row * DTOT + n0 + nf * 16 + l15] = f2bf(acc[mf][nf][reg]);
            }
            float s0 = 0.f, d0 = 0.f, s1 = 0.f, d1 = 0.f;
#pragma unroll
            for (int nf = 0; nf < 4; ++nf) {
                s0 += acc[mf][nf][reg] * as[nf];
                d0 += acc[mf][nf][reg] * ad[nf];
                s1 += acc[mf][nf + 4][reg] * as[nf + 4];
                d1 += acc[mf][nf + 4][reg] * ad[nf + 4];
            }
#pragma unroll
            for (int off = 1; off < 16; off <<= 1) {
                s0 += __shfl_xor(s0, off);
                d0 += __shfl_xor(d0, off);
                s1 += __shfl_xor(s1, off);
                d1 += __shfl_xor(d1, off);
            }
            if (ok && l15 == 0) {
                ls[row * HEADS + hb]      = s0;
                ld_[row * HEADS + hb]     = d0;
                ls[row * HEADS + hb + 1]  = s1;
                ld_[row * HEADS + hb + 1] = d1;
            }
        }
    }
}

// ---------------- attention softmax -> fp16 planes attnp[H][BINS] ----------------
// One wave per node; lanes = 16 edge-slots x 4 heads. deg<=64 => <=4 cached logits/lane.
__global__ __launch_bounds__(256) void k_attn(const int* __restrict__ cnt,
                                              const ushort* __restrict__ esrc,
                                              const float* __restrict__ ls,
                                              const float* __restrict__ ld_,
                                              _Float16* __restrict__ attnp) {
    int wv = threadIdx.x >> 6, lane = threadIdx.x & 63;
    int i = blockIdx.x * 4 + wv;
    if (i >= NNODES) return;
    int h = lane & 3, eo = lane >> 2;
    int deg = cnt[i]; if (deg > CAP) deg = CAP;
    int e0 = i << CAPLG, e1 = e0 + deg;
    float ldv = ld_[i * HEADS + h];
    float lv[4];
    float mx = -INFINITY;
#pragma unroll
    for (int r = 0; r < 4; ++r) {
        int e = e0 + eo + 16 * r;
        float v = -INFINITY;
        if (e < e1) {
            float l = ls[(int)esrc[e] * HEADS + h] + ldv;
            v = l > 0.f ? l : ALPHA * l;
        }
        lv[r] = v;
        mx = fmaxf(mx, v);
    }
    mx = fmaxf(mx, __shfl_xor(mx, 4));
    mx = fmaxf(mx, __shfl_xor(mx, 8));
    mx = fmaxf(mx, __shfl_xor(mx, 16));
    mx = fmaxf(mx, __shfl_xor(mx, 32));
    float p[4];
    float z = 0.f;
#pragma unroll
    for (int r = 0; r < 4; ++r) {
        p[r] = (lv[r] == -INFINITY) ? 0.f : __expf(lv[r] - mx);
        z += p[r];
    }
    z += __shfl_xor(z, 4);
    z += __shfl_xor(z, 8);
    z += __shfl_xor(z, 16);
    z += __shfl_xor(z, 32);
    float inv = 1.f / (z + 1e-16f);
#pragma unroll
    for (int r = 0; r < 4; ++r) {
        int e = e0 + eo + 16 * r;
        if (e < e1) attnp[(size_t)h * BINS + e] = (_Float16)(p[r] * inv);
    }
}

// ---------------- XCD-sliced gather: out[i, slice] = ELU(sum_e attn[e]*Wh[src_e, slice]) ----------------
// slice = blockIdx.x & 7 (32 channels) -> per-XCD Wh working set 3.2 MB (fits 4 MiB L2).
// Wave: 4 edge-groups x 16 lanes (uint = 2ch each); 16 nodes per wave.
__global__ __launch_bounds__(256) void k_gat_slice(const int* __restrict__ cnt,
                                                   const ushort* __restrict__ esrc,
                                                   const ushort* __restrict__ Whbf,
                                                   const _Float16* __restrict__ attnp,
                                                   ushort* __restrict__ out) {
    const int bx = blockIdx.x;
    const int s  = bx & 7;
    const int grp = bx >> 3;
    const int wv = threadIdx.x >> 6, lane = threadIdx.x & 63;
    const int eo = lane >> 4;          // 0..3
    const int cl = lane & 15;          // uint slot (2 ch)
    const int c0 = s * 32;
    const _Float16* ap = attnp + (size_t)(s >> 1) * BINS;
    const int nbase = grp * NGROUP + wv * (NGROUP / 4);
#pragma unroll 1
    for (int nn = 0; nn < NGROUP / 4; ++nn) {
        int i = nbase + nn;
        if (i >= NNODES) break;
        int deg = cnt[i]; if (deg > CAP) deg = CAP;
        int e0 = i << CAPLG, e1 = e0 + deg;
        float a0 = 0.f, a1 = 0.f;
        int e = e0 + eo;
        for (; e + 4 < e1; e += 8) {
            int s0 = (int)esrc[e], s1 = (int)esrc[e + 4];
            float p0 = (float)ap[e];
            float p1 = (float)ap[e + 4];
            unsigned u0 = *(const unsigned*)&Whbf[(size_t)s0 * DTOT + c0 + 2 * cl];
            unsigned u1 = *(const unsigned*)&Whbf[(size_t)s1 * DTOT + c0 + 2 * cl];
            a0 = fmaf(p0, blo(u0), a0); a1 = fmaf(p0, bhi(u0), a1);
            a0 = fmaf(p1, blo(u1), a0); a1 = fmaf(p1, bhi(u1), a1);
        }
        if (e < e1) {
            int s0 = (int)esrc[e];
            float p0 = (float)ap[e];
            unsigned u0 = *(const unsigned*)&Whbf[(size_t)s0 * DTOT + c0 + 2 * cl];
            a0 = fmaf(p0, blo(u0), a0); a1 = fmaf(p0, bhi(u0), a1);
        }
        a0 += __shfl_xor(a0, 16); a0 += __shfl_xor(a0, 32);
        a1 += __shfl_xor(a1, 16); a1 += __shfl_xor(a1, 32);
        if (eo == 0) {
            float v0 = a0 > 0.f ? a0 : __expf(a0) - 1.f;
            float v1 = a1 > 0.f ? a1 : __expf(a1) - 1.f;
            unsigned pk = (unsigned)f2bf(v0) | ((unsigned)f2bf(v1) << 16);
            *(unsigned*)&out[(size_t)i * DTOT + c0 + 2 * cl] = pk;
        }
    }
}

// ---------------- fused pooling + final linear ----------------
__global__ __launch_bounds__(1024) void k_pool_final(const ushort* __restrict__ h2bf,
                                                     const int* __restrict__ gstart,
                                                     const float* __restrict__ W,
                                                     const float* __restrict__ b,
                                                     float* __restrict__ out) {
    __shared__ float smx[4][256];
    __shared__ float ssm[4][256];
    __shared__ float pooled[2 * DTOT];
    int g = blockIdx.x, t = threadIdx.x;
    int c = t & 255, j = t >> 8;
    int s = gstart[g], e = gstart[g + 1];
    float mx = -INFINITY, sm = 0.f;
    for (int n = s + j; n < e; n += 4) {
        float vv = __uint_as_float(((unsigned)h2bf[(size_t)n * DTOT + c]) << 16);
        mx = fmaxf(mx, vv);
        sm += vv;
    }
    smx[j][c] = mx;
    ssm[j][c] = sm;
    __syncthreads();
    if (t < 256) {
        float m = fmaxf(fmaxf(smx[0][t], smx[1][t]), fmaxf(smx[2][t], smx[3][t]));
        float su = ssm[0][t] + ssm[1][t] + ssm[2][t] + ssm[3][t];
        int cnt = e - s;
        if (cnt <= 0) m = 0.f;
        pooled[t] = m;
        pooled[DTOT + t] = su / (float)(cnt > 0 ? cnt : 1);
    }
    __syncthreads();
    int wv = t >> 6, lane = t & 63;
    if (wv < NCLS) {
        float acc = 0.f;
        for (int k = lane; k < 2 * DTOT; k += 64)
            acc += pooled[k] * W[k * NCLS + wv];
#pragma unroll
        for (int off = 32; off; off >>= 1) acc += __shfl_down(acc, off);
        if (lane == 0)
            out[g * NCLS + wv] = acc + b[wv];
    }
}

extern "C" void kernel_launch(void* const* d_in, const int* in_sizes, int n_in,
                              void* d_out, int out_size, void* d_ws, size_t ws_size,
                              hipStream_t stream) {
    const float* x     = (const float*)d_in[0];
    const int*   ei    = (const int*)d_in[1];
    const int*   batch = (const int*)d_in[2];
    const float* W1    = (const float*)d_in[3];
    const float* a1s   = (const float*)d_in[4];
    const float* a1d   = (const float*)d_in[5];
    const float* W2    = (const float*)d_in[6];
    const float* a2s   = (const float*)d_in[7];
    const float* a2d   = (const float*)d_in[8];
    const float* linW  = (const float*)d_in[9];
    const float* linb  = (const float*)d_in[10];
    float* out = (float*)d_out;

    const int* src = ei;
    const int* dst = ei + NEDGES;

    size_t off = 0;
    char* base = (char*)d_ws;
    auto alloc = [&](size_t bytes) -> void* {
        void* p = base + off;
        off += (bytes + 255) & ~(size_t)255;
        return p;
    };
    ushort*    xbf    = (ushort*)alloc((size_t)NNODES * FIN * 2);
    ushort*    Whbf   = (ushort*)alloc((size_t)NNODES * DTOT * 2);
    ushort*    h1bf   = (ushort*)alloc((size_t)NNODES * DTOT * 2);
    ushort*    h2bf   = (ushort*)alloc((size_t)NNODES * DTOT * 2);
    float*     ls     = (float*)alloc((size_t)NNODES * HEADS * 4);
    float*     ld_    = (float*)alloc((size_t)NNODES * HEADS * 4);
    int*       cursor = (int*)alloc((size_t)NNODES * 4);
    ushort*    esrc   = (ushort*)alloc((size_t)BINS * 2);          // 6.4 MB bins
    _Float16*  attnp  = (_Float16*)alloc((size_t)HEADS * BINS * 2); // 25.6 MB
    int*       gstart = (int*)alloc((size_t)(NGRAPH + 1) * 4);
    ushort*    W1t    = (ushort*)alloc((size_t)DTOT * FIN * 2);
    ushort*    W2t    = (ushort*)alloc((size_t)DTOT * DTOT * 2);

    hipMemsetAsync(cursor, 0, (size_t)NNODES * 4, stream);

    int setup_blocks = EB + NB + XB + W1B + W2B;
    k_setup<<<setup_blocks, 256, 0, stream>>>(src, dst, cursor, esrc, batch, gstart,
                                              (const float4*)x, (ushort4*)xbf,
                                              W1, W1t, W2, W2t);

    dim3 ggrid(2, (NNODES + 127) / 128);
    int attn_blocks = (NNODES + 3) / 4;
    int gat_blocks  = GRPS * 8;

    // Layer 1
    k_gemm_mfma<FIN><<<ggrid, 256, 0, stream>>>(xbf, W1t, Whbf, ls, ld_, a1s, a1d, NNODES);
    k_attn<<<attn_blocks, 256, 0, stream>>>(cursor, esrc, ls, ld_, attnp);
    k_gat_slice<<<gat_blocks, 256, 0, stream>>>(cursor, esrc, Whbf, attnp, h1bf);

    // Layer 2
    k_gemm_mfma<DTOT><<<ggrid, 256, 0, stream>>>(h1bf, W2t, Whbf, ls, ld_, a2s, a2d, NNODES);
    k_attn<<<attn_blocks, 256, 0, stream>>>(cursor, esrc, ls, ld_, attnp);
    k_gat_slice<<<gat_blocks, 256, 0, stream>>>(cursor, esrc, Whbf, attnp, h2bf);

    // Pool + head (fused)
    k_pool_final<<<NGRAPH, 1024, 0, stream>>>(h2bf, gstart, linW, linb, out);
}

// Round 13
// 320.633 us; speedup vs baseline: 1.6531x; 1.6531x over previous
//
#include <hip/hip_runtime.h>
#include <hip/hip_bf16.h>

#define NNODES 50000
#define NEDGES 800000
#define FIN    128
#define HID    64
#define HEADS  4
#define NGRAPH 256
#define NCLS   10
#define DTOT   256   // HEADS*HID
#define ALPHA  0.01f
#define CAPLG  6          // 64 slots/node bin; Poisson(16) => P(deg>64) ~ 1e-20
#define CAP    (1 << CAPLG)

typedef short bf16x8 __attribute__((ext_vector_type(8)));
typedef float f32x4  __attribute__((ext_vector_type(4)));

#define NB      ((NNODES + 255) / 256)      // 196
#define EB      ((NEDGES + 255) / 256)      // 3125
#define XB      ((NNODES * FIN / 4 + 255) / 256)  // 6250
#define W1B     (FIN * DTOT / 256)          // 128
#define W2B     (DTOT * DTOT / 256)         // 256

__device__ __forceinline__ ushort f2bf(float v) {
    return __bfloat16_as_ushort(__float2bfloat16(v));
}
__device__ __forceinline__ float blo(unsigned u) { return __uint_as_float(u << 16); }
__device__ __forceinline__ float bhi(unsigned u) { return __uint_as_float(u & 0xffff0000u); }

// ---------------- fused setup: edge binning (ushort) | gstart | cast x | transpose W1,W2 ----------------
__global__ __launch_bounds__(256) void k_setup(const int* __restrict__ src, const int* __restrict__ dst,
                                               int* __restrict__ cursor, ushort* __restrict__ esrc,
                                               const int* __restrict__ batch, int* __restrict__ gstart,
                                               const float4* __restrict__ x4, ushort4* __restrict__ xbf4,
                                               const float* __restrict__ W1, ushort* __restrict__ W1t,
                                               const float* __restrict__ W2, ushort* __restrict__ W2t) {
    int b = blockIdx.x, t = threadIdx.x;
    if (b < EB) {
        int e = b * 256 + t;
        if (e < NEDGES) {
            int d = dst[e];
            int pos = atomicAdd(&cursor[d], 1);
            if (pos < CAP) esrc[(d << CAPLG) + pos] = (ushort)src[e];
        }
    } else if (b < EB + NB) {
        int i = (b - EB) * 256 + t;
        if (i >= NNODES) return;
        int bb = batch[i];
        if (i == 0) {
            for (int g = 0; g <= bb; ++g) gstart[g] = 0;
        } else {
            int pb = batch[i - 1];
            if (pb != bb) for (int g = pb + 1; g <= bb; ++g) gstart[g] = i;
        }
        if (i == NNODES - 1)
            for (int g = bb + 1; g <= NGRAPH; ++g) gstart[g] = NNODES;
    } else if (b < EB + NB + XB) {
        int i = (b - EB - NB) * 256 + t;
        if (i >= NNODES * FIN / 4) return;
        float4 v = x4[i];
        ushort4 o;
        o.x = f2bf(v.x); o.y = f2bf(v.y); o.z = f2bf(v.z); o.w = f2bf(v.w);
        xbf4[i] = o;
    } else if (b < EB + NB + XB + W1B) {
        int id = (b - EB - NB - XB) * 256 + t;
        int n = id & 255, k = id >> 8;
        W1t[n * FIN + (((k >> 3) ^ (n & 7)) << 3) + (k & 7)] = f2bf(W1[k * DTOT + n]);
    } else {
        int id = (b - EB - NB - XB - W1B) * 256 + t;
        int n = id & 255, k = id >> 8;
        W2t[n * DTOT + (((k >> 3) ^ (n & 7)) << 3) + (k & 7)] = f2bf(W2[k * DTOT + n]);
    }
}

// ---------------- MFMA GEMM: Cbf[M,256] = Abf[M,K] @ W[K,256], tile 128x128 (2 heads) ----------------
template <int K>
__global__ __launch_bounds__(256) void k_gemm_mfma(const ushort* __restrict__ Abf,
                                                   const ushort* __restrict__ Bt,
                                                   ushort* __restrict__ Cbf,
                                                   float* __restrict__ ls,
                                                   float* __restrict__ ld_,
                                                   const float* __restrict__ a_src,
                                                   const float* __restrict__ a_dst,
                                                   int M) {
    __shared__ ushort Bl[128 * K];
    const int tid  = threadIdx.x;
    const int w    = tid >> 6;
    const int lane = tid & 63;
    const int l15  = lane & 15;
    const int quad = lane >> 4;
    const int m0 = blockIdx.y * 128;
    const int n0 = blockIdx.x * 128;
    const int hb = blockIdx.x * 2;

    {
        const uint4* sp = (const uint4*)(Bt + (size_t)n0 * K);
        uint4* dp = (uint4*)Bl;
#pragma unroll
        for (int idx = tid; idx < 128 * K / 8; idx += 256) dp[idx] = sp[idx];
    }
    __syncthreads();

    f32x4 acc[2][8];
#pragma unroll
    for (int mf = 0; mf < 2; ++mf)
#pragma unroll
        for (int nf = 0; nf < 8; ++nf)
            acc[mf][nf] = (f32x4){0.f, 0.f, 0.f, 0.f};

    const int rbase = m0 + w * 32;
    int rowA0 = rbase + l15;       if (rowA0 >= M) rowA0 = M - 1;
    int rowA1 = rbase + 16 + l15;  if (rowA1 >= M) rowA1 = M - 1;
    const ushort* pa0 = Abf + (size_t)rowA0 * K + quad * 8;
    const ushort* pa1 = Abf + (size_t)rowA1 * K + quad * 8;

#pragma unroll
    for (int ks = 0; ks < K / 32; ++ks) {
        bf16x8 a0 = *(const bf16x8*)(pa0 + ks * 32);
        bf16x8 a1 = *(const bf16x8*)(pa1 + ks * 32);
        bf16x8 bfr[8];
#pragma unroll
        for (int nf = 0; nf < 8; ++nf) {
            int n = nf * 16 + l15;
            int c = (ks * 4 + quad) ^ (n & 7);
            bfr[nf] = *(const bf16x8*)&Bl[n * K + (c << 3)];
        }
#pragma unroll
        for (int nf = 0; nf < 8; ++nf) {
            acc[0][nf] = __builtin_amdgcn_mfma_f32_16x16x32_bf16(a0, bfr[nf], acc[0][nf], 0, 0, 0);
            acc[1][nf] = __builtin_amdgcn_mfma_f32_16x16x32_bf16(a1, bfr[nf], acc[1][nf], 0, 0, 0);
        }
    }

    float as[8], ad[8];
#pragma unroll
    for (int nf = 0; nf < 8; ++nf) {
        int head = hb + (nf >> 2);
        as[nf] = a_src[head * HID + (nf & 3) * 16 + l15];
        ad[nf] = a_dst[head * HID + (nf & 3) * 16 + l15];
    }
#pragma unroll
    for (int mf = 0; mf < 2; ++mf) {
#pragma unroll
        for (int reg = 0; reg < 4; ++reg) {
            int row = rbase + mf * 16 + quad * 4 + reg;
            bool ok = row < M;
            if (ok) {
#pragma unroll
                for (int nf = 0; nf < 8; ++nf)
                    Cbf[(size_t)row * DTOT + n0 + nf * 16 + l15] = f2bf(acc[mf][nf][reg]);
            }
            float s0 = 0.f, d0 = 0.f, s1 = 0.f, d1 = 0.f;
#pragma unroll
            for (int nf = 0; nf < 4; ++nf) {
                s0 += acc[mf][nf][reg] * as[nf];
                d0 += acc[mf][nf][reg] * ad[nf];
                s1 += acc[mf][nf + 4][reg] * as[nf + 4];
                d1 += acc[mf][nf + 4][reg] * ad[nf + 4];
            }
#pragma unroll
            for (int off = 1; off < 16; off <<= 1) {
                s0 += __shfl_xor(s0, off);
                d0 += __shfl_xor(d0, off);
                s1 += __shfl_xor(s1, off);
                d1 += __shfl_xor(d1, off);
            }
            if (ok && l15 == 0) {
                ls[row * HEADS + hb]      = s0;
                ld_[row * HEADS + hb]     = d0;
                ls[row * HEADS + hb + 1]  = s1;
                ld_[row * HEADS + hb + 1] = d1;
            }
        }
    }
}

// ---------------- fused softmax + gather-aggregate + ELU (round-11 form; ushort esrc) ----------------
__global__ __launch_bounds__(256) void k_gat_aggr(const int* __restrict__ cnt,
                                                  const ushort* __restrict__ esrc,
                                                  const ushort* __restrict__ Whbf,
                                                  const float* __restrict__ ls,
                                                  const float* __restrict__ ld_,
                                                  ushort* __restrict__ out) {
    const int wv   = threadIdx.x >> 6;
    const int lane = threadIdx.x & 63;
    const int i    = blockIdx.x * 4 + wv;
    if (i >= NNODES) return;
    const int half = lane >> 5;
    const int l32  = lane & 31;
    const int h    = l32 >> 3;
    const int e0 = i << CAPLG;
    int deg = cnt[i]; if (deg > CAP) deg = CAP;
    const int e1 = e0 + deg;
    const float ldv = ld_[i * HEADS + h];

    // pass A: M = lrelu(max_s ls[s,h] + ldv)   (lrelu monotone)
    float mx = -INFINITY;
    for (int e = e0 + (l32 & 7) + 8 * half; e < e1; e += 16)
        mx = fmaxf(mx, ls[(int)esrc[e] * HEADS + h]);
    mx = fmaxf(mx, __shfl_xor(mx, 1));
    mx = fmaxf(mx, __shfl_xor(mx, 2));
    mx = fmaxf(mx, __shfl_xor(mx, 4));
    mx = fmaxf(mx, __shfl_xor(mx, 32));
    float lvm = mx + ldv;
    const float M = lvm > 0.f ? lvm : ALPHA * lvm;

    float ac[8] = {};
    float z = 0.f;
    const int ch = 8 * l32;
    int e = e0 + half;
    for (; e + 6 < e1; e += 8) {
        int s0 = (int)esrc[e], s1 = (int)esrc[e + 2], s2 = (int)esrc[e + 4], s3 = (int)esrc[e + 6];
        float l0 = ls[s0 * HEADS + h] + ldv;
        float l1 = ls[s1 * HEADS + h] + ldv;
        float l2 = ls[s2 * HEADS + h] + ldv;
        float l3 = ls[s3 * HEADS + h] + ldv;
        uint4 u0 = *(const uint4*)&Whbf[(size_t)s0 * DTOT + ch];
        uint4 u1 = *(const uint4*)&Whbf[(size_t)s1 * DTOT + ch];
        uint4 u2 = *(const uint4*)&Whbf[(size_t)s2 * DTOT + ch];
        uint4 u3 = *(const uint4*)&Whbf[(size_t)s3 * DTOT + ch];
        float p0 = __expf((l0 > 0.f ? l0 : ALPHA * l0) - M);
        float p1 = __expf((l1 > 0.f ? l1 : ALPHA * l1) - M);
        float p2 = __expf((l2 > 0.f ? l2 : ALPHA * l2) - M);
        float p3 = __expf((l3 > 0.f ? l3 : ALPHA * l3) - M);
        z += p0 + p1 + p2 + p3;
        ac[0] = fmaf(p0, blo(u0.x), ac[0]); ac[1] = fmaf(p0, bhi(u0.x), ac[1]);
        ac[2] = fmaf(p0, blo(u0.y), ac[2]); ac[3] = fmaf(p0, bhi(u0.y), ac[3]);
        ac[4] = fmaf(p0, blo(u0.z), ac[4]); ac[5] = fmaf(p0, bhi(u0.z), ac[5]);
        ac[6] = fmaf(p0, blo(u0.w), ac[6]); ac[7] = fmaf(p0, bhi(u0.w), ac[7]);
        ac[0] = fmaf(p1, blo(u1.x), ac[0]); ac[1] = fmaf(p1, bhi(u1.x), ac[1]);
        ac[2] = fmaf(p1, blo(u1.y), ac[2]); ac[3] = fmaf(p1, bhi(u1.y), ac[3]);
        ac[4] = fmaf(p1, blo(u1.z), ac[4]); ac[5] = fmaf(p1, bhi(u1.z), ac[5]);
        ac[6] = fmaf(p1, blo(u1.w), ac[6]); ac[7] = fmaf(p1, bhi(u1.w), ac[7]);
        ac[0] = fmaf(p2, blo(u2.x), ac[0]); ac[1] = fmaf(p2, bhi(u2.x), ac[1]);
        ac[2] = fmaf(p2, blo(u2.y), ac[2]); ac[3] = fmaf(p2, bhi(u2.y), ac[3]);
        ac[4] = fmaf(p2, blo(u2.z), ac[4]); ac[5] = fmaf(p2, bhi(u2.z), ac[5]);
        ac[6] = fmaf(p2, blo(u2.w), ac[6]); ac[7] = fmaf(p2, bhi(u2.w), ac[7]);
        ac[0] = fmaf(p3, blo(u3.x), ac[0]); ac[1] = fmaf(p3, bhi(u3.x), ac[1]);
        ac[2] = fmaf(p3, blo(u3.y), ac[2]); ac[3] = fmaf(p3, bhi(u3.y), ac[3]);
        ac[4] = fmaf(p3, blo(u3.z), ac[4]); ac[5] = fmaf(p3, bhi(u3.z), ac[5]);
        ac[6] = fmaf(p3, blo(u3.w), ac[6]); ac[7] = fmaf(p3, bhi(u3.w), ac[7]);
    }
    for (; e < e1; e += 2) {
        int s0 = (int)esrc[e];
        float l0 = ls[s0 * HEADS + h] + ldv;
        uint4 u0 = *(const uint4*)&Whbf[(size_t)s0 * DTOT + ch];
        float p0 = __expf((l0 > 0.f ? l0 : ALPHA * l0) - M);
        z += p0;
        ac[0] = fmaf(p0, blo(u0.x), ac[0]); ac[1] = fmaf(p0, bhi(u0.x), ac[1]);
        ac[2] = fmaf(p0, blo(u0.y), ac[2]); ac[3] = fmaf(p0, bhi(u0.y), ac[3]);
        ac[4] = fmaf(p0, blo(u0.z), ac[4]); ac[5] = fmaf(p0, bhi(u0.z), ac[5]);
        ac[6] = fmaf(p0, blo(u0.w), ac[6]); ac[7] = fmaf(p0, bhi(u0.w), ac[7]);
    }

#pragma unroll
    for (int j = 0; j < 8; ++j) ac[j] += __shfl_xor(ac[j], 32);
    z += __shfl_xor(z, 32);

    if (half == 0) {
        const float inv = 1.f / (z + 1e-16f);
        float v[8];
#pragma unroll
        for (int j = 0; j < 8; ++j) {
            float t = ac[j] * inv;
            v[j] = t > 0.f ? t : __expf(t) - 1.f;
        }
        ushort4 pk, pk2;
        pk.x  = f2bf(v[0]); pk.y  = f2bf(v[1]); pk.z  = f2bf(v[2]); pk.w  = f2bf(v[3]);
        pk2.x = f2bf(v[4]); pk2.y = f2bf(v[5]); pk2.z = f2bf(v[6]); pk2.w = f2bf(v[7]);
        *(ushort4*)(out + (size_t)i * DTOT + ch)     = pk;
        *(ushort4*)(out + (size_t)i * DTOT + ch + 4) = pk2;
    }
}

// ---------------- fused pooling + final linear ----------------
__global__ __launch_bounds__(1024) void k_pool_final(const ushort* __restrict__ h2bf,
                                                     const int* __restrict__ gstart,
                                                     const float* __restrict__ W,
                                                     const float* __restrict__ b,
                                                     float* __restrict__ out) {
    __shared__ float smx[4][256];
    __shared__ float ssm[4][256];
    __shared__ float pooled[2 * DTOT];
    int g = blockIdx.x, t = threadIdx.x;
    int c = t & 255, j = t >> 8;
    int s = gstart[g], e = gstart[g + 1];
    float mx = -INFINITY, sm = 0.f;
    for (int n = s + j; n < e; n += 4) {
        float vv = __uint_as_float(((unsigned)h2bf[(size_t)n * DTOT + c]) << 16);
        mx = fmaxf(mx, vv);
        sm += vv;
    }
    smx[j][c] = mx;
    ssm[j][c] = sm;
    __syncthreads();
    if (t < 256) {
        float m = fmaxf(fmaxf(smx[0][t], smx[1][t]), fmaxf(smx[2][t], smx[3][t]));
        float su = ssm[0][t] + ssm[1][t] + ssm[2][t] + ssm[3][t];
        int cnt = e - s;
        if (cnt <= 0) m = 0.f;
        pooled[t] = m;
        pooled[DTOT + t] = su / (float)(cnt > 0 ? cnt : 1);
    }
    __syncthreads();
    int wv = t >> 6, lane = t & 63;
    if (wv < NCLS) {
        float acc = 0.f;
        for (int k = lane; k < 2 * DTOT; k += 64)
            acc += pooled[k] * W[k * NCLS + wv];
#pragma unroll
        for (int off = 32; off; off >>= 1) acc += __shfl_down(acc, off);
        if (lane == 0)
            out[g * NCLS + wv] = acc + b[wv];
    }
}

extern "C" void kernel_launch(void* const* d_in, const int* in_sizes, int n_in,
                              void* d_out, int out_size, void* d_ws, size_t ws_size,
                              hipStream_t stream) {
    const float* x     = (const float*)d_in[0];
    const int*   ei    = (const int*)d_in[1];
    const int*   batch = (const int*)d_in[2];
    const float* W1    = (const float*)d_in[3];
    const float* a1s   = (const float*)d_in[4];
    const float* a1d   = (const float*)d_in[5];
    const float* W2    = (const float*)d_in[6];
    const float* a2s   = (const float*)d_in[7];
    const float* a2d   = (const float*)d_in[8];
    const float* linW  = (const float*)d_in[9];
    const float* linb  = (const float*)d_in[10];
    float* out = (float*)d_out;

    const int* src = ei;
    const int* dst = ei + NEDGES;

    size_t off = 0;
    char* base = (char*)d_ws;
    auto alloc = [&](size_t bytes) -> void* {
        void* p = base + off;
        off += (bytes + 255) & ~(size_t)255;
        return p;
    };
    ushort* xbf    = (ushort*)alloc((size_t)NNODES * FIN * 2);
    ushort* Whbf   = (ushort*)alloc((size_t)NNODES * DTOT * 2);
    ushort* h1bf   = (ushort*)alloc((size_t)NNODES * DTOT * 2);
    ushort* h2bf   = (ushort*)alloc((size_t)NNODES * DTOT * 2);
    float*  ls     = (float*)alloc((size_t)NNODES * HEADS * 4);
    float*  ld_    = (float*)alloc((size_t)NNODES * HEADS * 4);
    int*    cursor = (int*)alloc((size_t)NNODES * 4);
    ushort* esrc   = (ushort*)alloc((size_t)(NNODES << CAPLG) * 2);  // 6.4 MB bins
    int*    gstart = (int*)alloc((size_t)(NGRAPH + 1) * 4);
    ushort* W1t    = (ushort*)alloc((size_t)DTOT * FIN * 2);
    ushort* W2t    = (ushort*)alloc((size_t)DTOT * DTOT * 2);

    hipMemsetAsync(cursor, 0, (size_t)NNODES * 4, stream);

    int setup_blocks = EB + NB + XB + W1B + W2B;
    k_setup<<<setup_blocks, 256, 0, stream>>>(src, dst, cursor, esrc, batch, gstart,
                                              (const float4*)x, (ushort4*)xbf,
                                              W1, W1t, W2, W2t);

    dim3 ggrid(2, (NNODES + 127) / 128);

    // Layer 1
    k_gemm_mfma<FIN><<<ggrid, 256, 0, stream>>>(xbf, W1t, Whbf, ls, ld_, a1s, a1d, NNODES);
    k_gat_aggr<<<(NNODES + 3) / 4, 256, 0, stream>>>(cursor, esrc, Whbf, ls, ld_, h1bf);

    // Layer 2
    k_gemm_mfma<DTOT><<<ggrid, 256, 0, stream>>>(h1bf, W2t, Whbf, ls, ld_, a2s, a2d, NNODES);
    k_gat_aggr<<<(NNODES + 3) / 4, 256, 0, stream>>>(cursor, esrc, Whbf, ls, ld_, h2bf);

    // Pool + head (fused)
    k_pool_final<<<NGRAPH, 1024, 0, stream>>>(h2bf, gstart, linW, linb, out);
}